// Round 8
// baseline (426.035 us; speedup 1.0000x reference)
//
#include <hip/hip_runtime.h>

#define B_ 512
#define L_ 512
#define N_ 128
#define TM 256          // fwd produces alpha_255, bwd produces beta_255
#define C_BIAS 3.0f
#define PAD 136         // f16 row stride for E in LDS: 272B, 16B-aligned, bank-spread

typedef _Float16 f16x8 __attribute__((ext_vector_type(8)));
typedef float    f32x4 __attribute__((ext_vector_type(4)));

// ---- DPP reductions ----
#define DPP_MAXS(v, ctrl)                                                       \
    {                                                                           \
        int _t = __builtin_amdgcn_update_dpp(__float_as_int(v),                 \
                    __float_as_int(v), ctrl, 0xf, 0xf, false);                  \
        v = fmaxf(v, __int_as_float(_t));                                       \
    }
#define DPP_ADDS(v, ctrl)                                                       \
    {                                                                           \
        int _t = __builtin_amdgcn_update_dpp(__float_as_int(v),                 \
                    __float_as_int(v), ctrl, 0xf, 0xf, false);                  \
        v = v + __int_as_float(_t);                                             \
    }

// max over each 16-lane row; result in all 16 lanes of the row
__device__ __forceinline__ float dpp16_max(float v) {
    DPP_MAXS(v, 0xB1);   // quad_perm [1,0,3,2]
    DPP_MAXS(v, 0x4E);   // quad_perm [2,3,0,1]
    DPP_MAXS(v, 0x141);  // row_half_mirror
    DPP_MAXS(v, 0x140);  // row_mirror
    return v;
}
// full 64-lane reductions (for path score / combine)
__device__ __forceinline__ float wave_max(float v) {
    DPP_MAXS(v, 0xB1); DPP_MAXS(v, 0x4E); DPP_MAXS(v, 0x141); DPP_MAXS(v, 0x140);
    DPP_MAXS(v, 0x142); DPP_MAXS(v, 0x143);
    return __int_as_float(__builtin_amdgcn_readlane(__float_as_int(v), 63));
}
__device__ __forceinline__ float wave_sum(float v) {
    DPP_ADDS(v, 0xB1); DPP_ADDS(v, 0x4E); DPP_ADDS(v, 0x141); DPP_ADDS(v, 0x140);
    DPP_ADDS(v, 0x142); DPP_ADDS(v, 0x143);
    return __int_as_float(__builtin_amdgcn_readlane(__float_as_int(v), 63));
}

__device__ __forceinline__ f32x4 vmax4(f32x4 a, f32x4 b) {
    f32x4 r;
    r[0] = fmaxf(a[0], b[0]); r[1] = fmaxf(a[1], b[1]);
    r[2] = fmaxf(a[2], b[2]); r[3] = fmaxf(a[3], b[3]);
    return r;
}

__device__ __forceinline__ float updf(float s, float mc, float emv, float mk, float ns) {
    float nxt = __logf(s) + mc + C_BIAS + emv;
    return mk * nxt + (1.f - mk) * ns;
}
__device__ __forceinline__ float updb(float s, float mc, float mk, float bs) {
    float u = __logf(s) + mc + C_BIAS;
    return mk * u + (1.f - mk) * bs;
}

// B-fragment loads (init only). fwd: B[k][n] = exp(trans[k][n]);
// bwd: B[k=j][n=i] = exp(trans[i=n][j=k]).
__device__ __forceinline__ f16x8 ldb_fwd(const float* __restrict__ trans, int kbase, int n) {
    f16x8 f;
#pragma unroll
    for (int jj = 0; jj < 8; ++jj) f[jj] = (_Float16)__expf(trans[(kbase + jj) * N_ + n]);
    return f;
}
__device__ __forceinline__ f16x8 ldb_bwd(const float* __restrict__ trans, int kbase, int n) {
    f16x8 f;
#pragma unroll
    for (int jj = 0; jj < 8; ++jj) f[jj] = (_Float16)__expf(trans[n * N_ + kbase + jj]);
    return f;
}

// LDS-only barrier: no vmcnt drain -> global prefetches ride across.
__device__ __forceinline__ void lds_barrier() {
    asm volatile("s_waitcnt lgkmcnt(0)\n\ts_barrier" ::: "memory");
}

// ---------------------------------------------------------------------------
// norm_kernel: 64 blocks x 256 threads (4 waves). Block g handles 16 batches;
// blocks 0..31 = forward half (t=0..255), 32..63 = backward half (t=511..255).
// Step = S(16x128) = E(16x128) x ET(128x128) via mfma_f32_16x16x32_f16:
//   wave w owns output cols [32w,32w+32) (2 N-tiles); ET B-frags persistent
//   in 32 VGPRs; E in LDS A-layout (parity dbuf); scores in C-layout regs.
// Per-batch lag-1 max via dpp16 + cross-wave LDS float4 (scheme of r4-r7,
// absmax 0.0). One LDS-only barrier per step.
// ---------------------------------------------------------------------------
__global__ __launch_bounds__(256, 1) void norm_kernel(
    const float* __restrict__ em, const int* __restrict__ tg,
    const float* __restrict__ mask, const float* __restrict__ st,
    const float* __restrict__ trans,
    float* __restrict__ alpha, float* __restrict__ beta,
    float* __restrict__ pathf, float* __restrict__ pathb)
{
    __shared__ __align__(16) _Float16 Eh[2][16 * PAD];   // E/F matrix, parity dbuf
    __shared__ __align__(16) float pmax[2][4][16];       // per-wave per-batch max
    __shared__ __align__(16) float mlds[TM][16];         // mask[t][m]

    const int tid  = threadIdx.x;
    const int wv   = tid >> 6;
    const int l    = tid & 63;
    const int col  = l & 15;        // A-row m for reads / C-col n
    const int quad = l >> 4;        // 0..3
    const int isb  = (blockIdx.x >= 32);
    const int blk  = blockIdx.x & 31;
    const int b16  = blk * 16;
    const int toff = isb ? TM : 0;

    // ---- stage mask[t][m] ----
#pragma unroll
    for (int i = 0; i < 16; ++i)
        mlds[tid][i] = mask[(size_t)(b16 + i) * L_ + toff + tid];

    // ---- path score: wave wv handles batches b16 + wv*4 + r ----
#pragma unroll
    for (int r = 0; r < 4; ++r) {
        int bb = b16 + wv * 4 + r;
        float pacc = 0.f;
        if (!isb) {
            for (int t = 1 + l; t < TM; t += 64) {
                int cur  = tg[bb * L_ + t];
                int prev = tg[bb * L_ + t - 1];
                pacc += mask[bb * L_ + t] *
                        (trans[prev * N_ + cur] + em[((size_t)bb * L_ + t) * N_ + cur]);
            }
            pacc = wave_sum(pacc);
            if (l == 0) {
                int t0 = tg[bb * L_];
                pathf[bb] = pacc + st[t0] + em[(size_t)bb * L_ * N_ + t0];
            }
        } else {
            for (int t = TM + l; t < L_; t += 64) {
                int cur  = tg[bb * L_ + t];
                int prev = tg[bb * L_ + t - 1];
                pacc += mask[bb * L_ + t] *
                        (trans[prev * N_ + cur] + em[((size_t)bb * L_ + t) * N_ + cur]);
            }
            pacc = wave_sum(pacc);
            if (l == 0) pathb[bb] = pacc;
        }
    }

    // ---- persistent B-fragments (ET), 2 tiles x 4 K-chunks ----
    const int n0 = wv * 32 + col;        // output state, tile 0
    const int n1 = n0 + 16;              // tile 1
    const int kb = quad * 8;
    f16x8 b0k0, b0k1, b0k2, b0k3, b1k0, b1k1, b1k2, b1k3;
    if (!isb) {
        b0k0 = ldb_fwd(trans, 0  + kb, n0); b0k1 = ldb_fwd(trans, 32 + kb, n0);
        b0k2 = ldb_fwd(trans, 64 + kb, n0); b0k3 = ldb_fwd(trans, 96 + kb, n0);
        b1k0 = ldb_fwd(trans, 0  + kb, n1); b1k1 = ldb_fwd(trans, 32 + kb, n1);
        b1k2 = ldb_fwd(trans, 64 + kb, n1); b1k3 = ldb_fwd(trans, 96 + kb, n1);
    } else {
        b0k0 = ldb_bwd(trans, 0  + kb, n0); b0k1 = ldb_bwd(trans, 32 + kb, n0);
        b0k2 = ldb_bwd(trans, 64 + kb, n0); b0k3 = ldb_bwd(trans, 96 + kb, n0);
        b1k0 = ldb_bwd(trans, 0  + kb, n1); b1k1 = ldb_bwd(trans, 32 + kb, n1);
        b1k2 = ldb_bwd(trans, 64 + kb, n1); b1k3 = ldb_bwd(trans, 96 + kb, n1);
    }

    // per-lane emission bases (batch = b16 + quad*4 + r, state n0; +16 for n1)
    const size_t a0 = ((size_t)(b16 + quad * 4 + 0) * L_) * N_ + n0;
    const size_t a1 = ((size_t)(b16 + quad * 4 + 1) * L_) * N_ + n0;
    const size_t a2 = ((size_t)(b16 + quad * 4 + 2) * L_) * N_ + n0;
    const size_t a3 = ((size_t)(b16 + quad * 4 + 3) * L_) * N_ + n0;

    f32x4 ns0, ns1;    // scores (fwd: alpha; bwd: v = beta + em), C-layout
    f32x4 bs0, bs1;    // bwd beta
    f32x4 Mc;          // lag carry per batch

    // ---- init scores at t=0 (fwd) / t=511 (bwd) ----
    if (!isb) {
        float st0 = st[n0], st1 = st[n1];
        ns0[0] = st0 + em[a0]; ns1[0] = st1 + em[a0 + 16];
        ns0[1] = st0 + em[a1]; ns1[1] = st1 + em[a1 + 16];
        ns0[2] = st0 + em[a2]; ns1[2] = st1 + em[a2 + 16];
        ns0[3] = st0 + em[a3]; ns1[3] = st1 + em[a3 + 16];
    } else {
        size_t t511 = (size_t)(L_ - 1) * N_;
        bs0[0] = 0.f; bs0[1] = 0.f; bs0[2] = 0.f; bs0[3] = 0.f;
        bs1 = bs0;
        ns0[0] = em[a0 + t511]; ns1[0] = em[a0 + t511 + 16];
        ns0[1] = em[a1 + t511]; ns1[1] = em[a1 + t511 + 16];
        ns0[2] = em[a2 + t511]; ns1[2] = em[a2 + t511 + 16];
        ns0[3] = em[a3 + t511]; ns1[3] = em[a3 + t511 + 16];
    }
    {
        f32x4 mx = vmax4(ns0, ns1);
        mx[0] = dpp16_max(mx[0]); mx[1] = dpp16_max(mx[1]);
        mx[2] = dpp16_max(mx[2]); mx[3] = dpp16_max(mx[3]);
        if (col == 0) *(f32x4*)&pmax[0][wv][quad * 4] = mx;
    }
    __syncthreads();
    {
        const float* pmr = &pmax[0][0][0] + quad * 4;
        f32x4 q0 = *(const f32x4*)(pmr);
        f32x4 q1 = *(const f32x4*)(pmr + 16);
        f32x4 q2 = *(const f32x4*)(pmr + 32);
        f32x4 q3 = *(const f32x4*)(pmr + 48);
        Mc = vmax4(vmax4(q0, q1), vmax4(q2, q3));   // exact M at boundary
        _Float16* Ewp = Eh[0];
        Ewp[(quad * 4 + 0) * PAD + n0] = (_Float16)__expf(ns0[0] - Mc[0] - C_BIAS);
        Ewp[(quad * 4 + 0) * PAD + n1] = (_Float16)__expf(ns1[0] - Mc[0] - C_BIAS);
        Ewp[(quad * 4 + 1) * PAD + n0] = (_Float16)__expf(ns0[1] - Mc[1] - C_BIAS);
        Ewp[(quad * 4 + 1) * PAD + n1] = (_Float16)__expf(ns1[1] - Mc[1] - C_BIAS);
        Ewp[(quad * 4 + 2) * PAD + n0] = (_Float16)__expf(ns0[2] - Mc[2] - C_BIAS);
        Ewp[(quad * 4 + 2) * PAD + n1] = (_Float16)__expf(ns1[2] - Mc[2] - C_BIAS);
        Ewp[(quad * 4 + 3) * PAD + n0] = (_Float16)__expf(ns0[3] - Mc[3] - C_BIAS);
        Ewp[(quad * 4 + 3) * PAD + n1] = (_Float16)__expf(ns1[3] - Mc[3] - C_BIAS);
    }

#define MMCHAIN(RD)                                                             \
    f32x4 acc0 = {0.f, 0.f, 0.f, 0.f};                                          \
    f32x4 acc1 = {0.f, 0.f, 0.f, 0.f};                                          \
    {                                                                           \
        const _Float16* Eb = Eh[RD] + col * PAD + quad * 8;                     \
        f16x8 afr;                                                              \
        afr = *(const f16x8*)(Eb);                                              \
        acc0 = __builtin_amdgcn_mfma_f32_16x16x32_f16(afr, b0k0, acc0, 0, 0, 0);\
        acc1 = __builtin_amdgcn_mfma_f32_16x16x32_f16(afr, b1k0, acc1, 0, 0, 0);\
        afr = *(const f16x8*)(Eb + 32);                                         \
        acc0 = __builtin_amdgcn_mfma_f32_16x16x32_f16(afr, b0k1, acc0, 0, 0, 0);\
        acc1 = __builtin_amdgcn_mfma_f32_16x16x32_f16(afr, b1k1, acc1, 0, 0, 0);\
        afr = *(const f16x8*)(Eb + 64);                                         \
        acc0 = __builtin_amdgcn_mfma_f32_16x16x32_f16(afr, b0k2, acc0, 0, 0, 0);\
        acc1 = __builtin_amdgcn_mfma_f32_16x16x32_f16(afr, b1k2, acc1, 0, 0, 0);\
        afr = *(const f16x8*)(Eb + 96);                                         \
        acc0 = __builtin_amdgcn_mfma_f32_16x16x32_f16(afr, b0k3, acc0, 0, 0, 0);\
        acc1 = __builtin_amdgcn_mfma_f32_16x16x32_f16(afr, b1k3, acc1, 0, 0, 0);\
    }

#define RDMS(RD)                                                                \
    const float* pmr = &pmax[RD][0][0] + quad * 4;                              \
    f32x4 q0 = *(const f32x4*)(pmr);                                            \
    f32x4 q1 = *(const f32x4*)(pmr + 16);                                       \
    f32x4 q2 = *(const f32x4*)(pmr + 32);                                       \
    f32x4 q3 = *(const f32x4*)(pmr + 48);                                       \
    f32x4 Ms = vmax4(vmax4(q0, q1), vmax4(q2, q3));

#define WREXP(WR, V0, V1)                                                       \
    {                                                                           \
        _Float16* Ewp = Eh[WR];                                                 \
        Ewp[(quad * 4 + 0) * PAD + n0] = (_Float16)__expf(V0[0] - Ms[0] - C_BIAS); \
        Ewp[(quad * 4 + 0) * PAD + n1] = (_Float16)__expf(V1[0] - Ms[0] - C_BIAS); \
        Ewp[(quad * 4 + 1) * PAD + n0] = (_Float16)__expf(V0[1] - Ms[1] - C_BIAS); \
        Ewp[(quad * 4 + 1) * PAD + n1] = (_Float16)__expf(V1[1] - Ms[1] - C_BIAS); \
        Ewp[(quad * 4 + 2) * PAD + n0] = (_Float16)__expf(V0[2] - Ms[2] - C_BIAS); \
        Ewp[(quad * 4 + 2) * PAD + n1] = (_Float16)__expf(V1[2] - Ms[2] - C_BIAS); \
        Ewp[(quad * 4 + 3) * PAD + n0] = (_Float16)__expf(V0[3] - Ms[3] - C_BIAS); \
        Ewp[(quad * 4 + 3) * PAD + n1] = (_Float16)__expf(V1[3] - Ms[3] - C_BIAS); \
        f32x4 mx = vmax4(V0, V1);                                               \
        mx[0] = dpp16_max(mx[0]); mx[1] = dpp16_max(mx[1]);                     \
        mx[2] = dpp16_max(mx[2]); mx[3] = dpp16_max(mx[3]);                     \
        if (col == 0) *(f32x4*)&pmax[WR][wv][quad * 4] = mx;                    \
        Mc = Ms;                                                                \
    }

    if (!isb) {
        // =============== FORWARD: t = 1..255 ===============
        f32x4 SA0, SA1, SB0, SB1;
        SA0[0] = em[a0 + (size_t)1 * N_]; SA1[0] = em[a0 + (size_t)1 * N_ + 16];
        SA0[1] = em[a1 + (size_t)1 * N_]; SA1[1] = em[a1 + (size_t)1 * N_ + 16];
        SA0[2] = em[a2 + (size_t)1 * N_]; SA1[2] = em[a2 + (size_t)1 * N_ + 16];
        SA0[3] = em[a3 + (size_t)1 * N_]; SA1[3] = em[a3 + (size_t)1 * N_ + 16];
        SB0[0] = em[a0 + (size_t)2 * N_]; SB1[0] = em[a0 + (size_t)2 * N_ + 16];
        SB0[1] = em[a1 + (size_t)2 * N_]; SB1[1] = em[a1 + (size_t)2 * N_ + 16];
        SB0[2] = em[a2 + (size_t)2 * N_]; SB1[2] = em[a2 + (size_t)2 * N_ + 16];
        SB0[3] = em[a3 + (size_t)2 * N_]; SB1[3] = em[a3 + (size_t)2 * N_ + 16];

#define STEPF(T, RD, WR, SL0, SL1)                                              \
        {                                                                       \
            lds_barrier();                                                      \
            f32x4 emv0 = SL0, emv1 = SL1;                                       \
            int tpf = (T) + 2; if (tpf > TM - 1) tpf = TM - 1;                  \
            size_t tofs = (size_t)tpf * N_;                                     \
            SL0[0] = em[a0 + tofs]; SL1[0] = em[a0 + tofs + 16];                \
            SL0[1] = em[a1 + tofs]; SL1[1] = em[a1 + tofs + 16];                \
            SL0[2] = em[a2 + tofs]; SL1[2] = em[a2 + tofs + 16];                \
            SL0[3] = em[a3 + tofs]; SL1[3] = em[a3 + tofs + 16];                \
            RDMS(RD);                                                           \
            f32x4 mk4 = *(const f32x4*)&mlds[T][quad * 4];                      \
            MMCHAIN(RD);                                                        \
            ns0[0] = updf(acc0[0], Mc[0], emv0[0], mk4[0], ns0[0]);             \
            ns0[1] = updf(acc0[1], Mc[1], emv0[1], mk4[1], ns0[1]);             \
            ns0[2] = updf(acc0[2], Mc[2], emv0[2], mk4[2], ns0[2]);             \
            ns0[3] = updf(acc0[3], Mc[3], emv0[3], mk4[3], ns0[3]);             \
            ns1[0] = updf(acc1[0], Mc[0], emv1[0], mk4[0], ns1[0]);             \
            ns1[1] = updf(acc1[1], Mc[1], emv1[1], mk4[1], ns1[1]);             \
            ns1[2] = updf(acc1[2], Mc[2], emv1[2], mk4[2], ns1[2]);             \
            ns1[3] = updf(acc1[3], Mc[3], emv1[3], mk4[3], ns1[3]);             \
            WREXP(WR, ns0, ns1);                                                \
        }

        for (int t = 1; t + 1 < TM; t += 2) {
            STEPF(t,     0, 1, SA0, SA1);
            STEPF(t + 1, 1, 0, SB0, SB1);
        }
        STEPF(TM - 1, 0, 1, SA0, SA1);
#undef STEPF

        alpha[(size_t)(b16 + quad * 4 + 0) * N_ + n0] = ns0[0];
        alpha[(size_t)(b16 + quad * 4 + 0) * N_ + n1] = ns1[0];
        alpha[(size_t)(b16 + quad * 4 + 1) * N_ + n0] = ns0[1];
        alpha[(size_t)(b16 + quad * 4 + 1) * N_ + n1] = ns1[1];
        alpha[(size_t)(b16 + quad * 4 + 2) * N_ + n0] = ns0[2];
        alpha[(size_t)(b16 + quad * 4 + 2) * N_ + n1] = ns1[2];
        alpha[(size_t)(b16 + quad * 4 + 3) * N_ + n0] = ns0[3];
        alpha[(size_t)(b16 + quad * 4 + 3) * N_ + n1] = ns1[3];
    } else {
        // =============== BACKWARD: t = 510..255 ===============
        f32x4 SA0, SA1, SB0, SB1;
        SA0[0] = em[a0 + (size_t)510 * N_]; SA1[0] = em[a0 + (size_t)510 * N_ + 16];
        SA0[1] = em[a1 + (size_t)510 * N_]; SA1[1] = em[a1 + (size_t)510 * N_ + 16];
        SA0[2] = em[a2 + (size_t)510 * N_]; SA1[2] = em[a2 + (size_t)510 * N_ + 16];
        SA0[3] = em[a3 + (size_t)510 * N_]; SA1[3] = em[a3 + (size_t)510 * N_ + 16];
        SB0[0] = em[a0 + (size_t)509 * N_]; SB1[0] = em[a0 + (size_t)509 * N_ + 16];
        SB0[1] = em[a1 + (size_t)509 * N_]; SB1[1] = em[a1 + (size_t)509 * N_ + 16];
        SB0[2] = em[a2 + (size_t)509 * N_]; SB1[2] = em[a2 + (size_t)509 * N_ + 16];
        SB0[3] = em[a3 + (size_t)509 * N_]; SB1[3] = em[a3 + (size_t)509 * N_ + 16];

#define STEPB(T, RD, WR, SL0, SL1)                                              \
        {                                                                       \
            lds_barrier();                                                      \
            f32x4 emv0 = SL0, emv1 = SL1;                                       \
            int tpf = (T) - 2; if (tpf < TM - 1) tpf = TM - 1;                  \
            size_t tofs = (size_t)tpf * N_;                                     \
            SL0[0] = em[a0 + tofs]; SL1[0] = em[a0 + tofs + 16];                \
            SL0[1] = em[a1 + tofs]; SL1[1] = em[a1 + tofs + 16];                \
            SL0[2] = em[a2 + tofs]; SL1[2] = em[a2 + tofs + 16];                \
            SL0[3] = em[a3 + tofs]; SL1[3] = em[a3 + tofs + 16];                \
            RDMS(RD);                                                           \
            f32x4 mk4 = *(const f32x4*)&mlds[(T) + 1 - TM][quad * 4];           \
            MMCHAIN(RD);                                                        \
            bs0[0] = updb(acc0[0], Mc[0], mk4[0], bs0[0]);                      \
            bs0[1] = updb(acc0[1], Mc[1], mk4[1], bs0[1]);                      \
            bs0[2] = updb(acc0[2], Mc[2], mk4[2], bs0[2]);                      \
            bs0[3] = updb(acc0[3], Mc[3], mk4[3], bs0[3]);                      \
            bs1[0] = updb(acc1[0], Mc[0], mk4[0], bs1[0]);                      \
            bs1[1] = updb(acc1[1], Mc[1], mk4[1], bs1[1]);                      \
            bs1[2] = updb(acc1[2], Mc[2], mk4[2], bs1[2]);                      \
            bs1[3] = updb(acc1[3], Mc[3], mk4[3], bs1[3]);                      \
            ns0[0] = bs0[0] + emv0[0]; ns1[0] = bs1[0] + emv1[0];               \
            ns0[1] = bs0[1] + emv0[1]; ns1[1] = bs1[1] + emv1[1];               \
            ns0[2] = bs0[2] + emv0[2]; ns1[2] = bs1[2] + emv1[2];               \
            ns0[3] = bs0[3] + emv0[3]; ns1[3] = bs1[3] + emv1[3];               \
            WREXP(WR, ns0, ns1);                                                \
        }

        for (int t = 510; t >= 256; t -= 2) {
            STEPB(t,     0, 1, SA0, SA1);
            STEPB(t - 1, 1, 0, SB0, SB1);
        }
#undef STEPB

        beta[(size_t)(b16 + quad * 4 + 0) * N_ + n0] = bs0[0];
        beta[(size_t)(b16 + quad * 4 + 0) * N_ + n1] = bs1[0];
        beta[(size_t)(b16 + quad * 4 + 1) * N_ + n0] = bs0[1];
        beta[(size_t)(b16 + quad * 4 + 1) * N_ + n1] = bs1[1];
        beta[(size_t)(b16 + quad * 4 + 2) * N_ + n0] = bs0[2];
        beta[(size_t)(b16 + quad * 4 + 2) * N_ + n1] = bs1[2];
        beta[(size_t)(b16 + quad * 4 + 3) * N_ + n0] = bs0[3];
        beta[(size_t)(b16 + quad * 4 + 3) * N_ + n1] = bs1[3];
    }
}

// ---------------------------------------------------------------------------
__global__ __launch_bounds__(1024) void combine_kernel(
    const float* __restrict__ alpha, const float* __restrict__ beta,
    const float* __restrict__ pathf, const float* __restrict__ pathb,
    float* __restrict__ out)
{
    __shared__ float part[16];
    const int tid = threadIdx.x;
    const int w = tid >> 6;
    const int l = tid & 63;
    float acc = 0.f;
    for (int k = 0; k < 32; ++k) {
        int b = w * 32 + k;
        float2 av = *(const float2*)(alpha + b * N_ + 2 * l);
        float2 bv = *(const float2*)(beta  + b * N_ + 2 * l);
        float v0 = av.x + bv.x;
        float v1 = av.y + bv.y;
        float m = wave_max(fmaxf(v0, v1));
        float s = wave_sum(__expf(v0 - m) + __expf(v1 - m));
        if (l == 0) acc += m + __logf(s) - pathf[b] - pathb[b];
    }
    if (l == 0) part[w] = acc;
    __syncthreads();
    if (tid == 0) {
        float t = 0.f;
#pragma unroll
        for (int i = 0; i < 16; ++i) t += part[i];
        out[0] = t / (float)B_;
    }
}

// ---------------------------------------------------------------------------
extern "C" void kernel_launch(void* const* d_in, const int* in_sizes, int n_in,
                              void* d_out, int out_size, void* d_ws, size_t ws_size,
                              hipStream_t stream) {
    const float* emission    = (const float*)d_in[0];
    const int*   target      = (const int*)  d_in[1];
    const float* mask        = (const float*)d_in[2];
    const float* start_trans = (const float*)d_in[3];
    const float* trans       = (const float*)d_in[4];
    float* out = (float*)d_out;

    float* ws_f  = (float*)d_ws;
    float* alpha = ws_f;                    // 512*128
    float* beta  = ws_f + B_ * N_;          // 512*128
    float* pathf = ws_f + 2 * B_ * N_;      // 512
    float* pathb = ws_f + 2 * B_ * N_ + B_; // 512

    norm_kernel   <<<64, 256, 0, stream>>>(emission, target, mask, start_trans,
                                           trans, alpha, beta, pathf, pathb);
    combine_kernel<<<1, 1024, 0, stream>>>(alpha, beta, pathf, pathb, out);
}

// Round 9
// 362.371 us; speedup vs baseline: 1.1757x; 1.1757x over previous
//
#include <hip/hip_runtime.h>

#define B_ 512
#define L_ 512
#define N_ 128
#define TM 256          // boundary: fwd produces alpha_255, bwd produces beta_255
#define C_BIAS 3.0f

typedef _Float16 h2_t __attribute__((ext_vector_type(2)));
typedef unsigned int u32v __attribute__((ext_vector_type(32)));  // 32 packed h2 = 64 f16

__device__ __forceinline__ unsigned packh2(float x, float y) {
    h2_t h; h[0] = (_Float16)x; h[1] = (_Float16)y;
    return __builtin_bit_cast(unsigned, h);
}

// v_dot2_f32_f16 with explicit "v" (arch VGPR) constraints: forces the ET
// operand out of AGPR homes (r5-r7: compiler homed the 64-reg ET fragment in
// AGPRs -> 64 v_accvgpr_read per step = ~55% of VALU issue).
__device__ __forceinline__ void dot2a(float& acc, unsigned a, unsigned b) {
    asm("v_dot2_f32_f16 %0, %1, %2, %0" : "+v"(acc) : "v"(a), "v"(b));
}

// ---- full-rate VALU wave-64 reductions via DPP ----
#define DPP_STEP_MAX(v, ctrl)                                                   \
    {                                                                           \
        int _t = __builtin_amdgcn_update_dpp(__float_as_int(v),                 \
                    __float_as_int(v), ctrl, 0xf, 0xf, false);                  \
        v = fmaxf(v, __int_as_float(_t));                                       \
    }
#define DPP_STEP_ADD(v, ctrl)                                                   \
    {                                                                           \
        int _t = __builtin_amdgcn_update_dpp(__float_as_int(v),                 \
                    __float_as_int(v), ctrl, 0xf, 0xf, false);                  \
        v = v + __int_as_float(_t);                                             \
    }

__device__ __forceinline__ float wave_max(float v) {
    DPP_STEP_MAX(v, 0xB1);   // quad_perm [1,0,3,2]
    DPP_STEP_MAX(v, 0x4E);   // quad_perm [2,3,0,1]
    DPP_STEP_MAX(v, 0x141);  // row_half_mirror
    DPP_STEP_MAX(v, 0x140);  // row_mirror
    DPP_STEP_MAX(v, 0x142);  // row_bcast15
    DPP_STEP_MAX(v, 0x143);  // row_bcast31
    return __int_as_float(__builtin_amdgcn_readlane(__float_as_int(v), 63));
}
__device__ __forceinline__ float wave_sum(float v) {
    DPP_STEP_ADD(v, 0xB1);
    DPP_STEP_ADD(v, 0x4E);
    DPP_STEP_ADD(v, 0x141);
    DPP_STEP_ADD(v, 0x140);
    DPP_STEP_ADD(v, 0x142);
    DPP_STEP_ADD(v, 0x143);
    return __int_as_float(__builtin_amdgcn_readlane(__float_as_int(v), 63));
}

// LDS-only barrier: waits lgkmcnt(0) but does NOT drain vmcnt -> global
// prefetch loads stay in flight across the barrier.
__device__ __forceinline__ void lds_barrier() {
    asm volatile("s_waitcnt lgkmcnt(0)\n\ts_barrier" ::: "memory");
}

// s = sum over 128 states: E[pair p] . ET[pair p]; ET in arch VGPRs via dot2a.
__device__ __forceinline__ float dot128(const h2_t* Erd, u32v ua, u32v ub) {
    const uint4* E4 = (const uint4*)Erd;
    float a0 = 0.f, a1 = 0.f, a2 = 0.f, a3 = 0.f;
    float a4 = 0.f, a5 = 0.f, a6 = 0.f, a7 = 0.f;
#pragma unroll
    for (int r = 0; r < 8; ++r) {
        uint4 blk = E4[r];
        dot2a(a0, blk.x, ua[4 * r + 0]);
        dot2a(a1, blk.y, ua[4 * r + 1]);
        dot2a(a2, blk.z, ua[4 * r + 2]);
        dot2a(a3, blk.w, ua[4 * r + 3]);
    }
#pragma unroll
    for (int r = 0; r < 8; ++r) {
        uint4 blk = E4[8 + r];
        dot2a(a4, blk.x, ub[4 * r + 0]);
        dot2a(a5, blk.y, ub[4 * r + 1]);
        dot2a(a6, blk.z, ub[4 * r + 2]);
        dot2a(a7, blk.w, ub[4 * r + 3]);
    }
    return ((a0 + a1) + (a2 + a3)) + ((a4 + a5) + (a6 + a7));
}

// ---------------------------------------------------------------------------
// norm_kernel: 1024 blocks x 128 threads (2 waves) = 2 waves/SIMD.
// b = blockIdx>>1 ; bw = blockIdx&1 (0 = fwd t=0..255, 1 = bwd t=511..255).
// Lane owns ONE state (tid). ET fragment in two u32v vectors, consumed via
// asm dot2 with "v" constraints. E/F vector + per-step max exchanged through
// parity double-buffered LDS; one LDS-only barrier per step. Lag-1 max
// normalization (validated absmax 0.0 in rounds 4-8).
// ---------------------------------------------------------------------------
__global__ __launch_bounds__(128, 2) void norm_kernel(
    const float* __restrict__ em, const int* __restrict__ tg,
    const float* __restrict__ mask, const float* __restrict__ st,
    const float* __restrict__ trans,
    float* __restrict__ alpha, float* __restrict__ beta,
    float* __restrict__ pathf, float* __restrict__ pathb)
{
    __shared__ __align__(16) h2_t Ehb[2][64];   // E/F vector, parity buffered
    __shared__ __align__(8)  float pm2[2][2];   // per-wave max, parity buffered
    __shared__ float Mlds[TM];                  // mask half-row
    __shared__ float pred[2];

    const int tid = threadIdx.x;     // == state index
    const int w   = tid >> 6;
    const int l   = tid & 63;
    const int b   = blockIdx.x >> 1;
    const int bw  = blockIdx.x & 1;
    const size_t base = (size_t)b * L_ * N_;
    const int bL = b * L_;

    if (bw == 0) {
        // ================= FORWARD =================
        float pacc = 0.f;
        for (int t = 1 + tid; t < TM; t += 128) {
            int cur  = tg[bL + t];
            int prev = tg[bL + t - 1];
            pacc += mask[bL + t] * (trans[prev * N_ + cur] + em[base + (size_t)t * N_ + cur]);
        }
        pacc = wave_sum(pacc);
        if (l == 0) pred[w] = pacc;

        Mlds[tid]       = mask[bL + tid];
        Mlds[tid + 128] = mask[bL + tid + 128];

        // ET column fragment (states i paired): ua pair k = (i=2k, 2k+1), ub: i+64
        u32v ua, ub;
#pragma unroll
        for (int k = 0; k < 32; ++k) {
            ua[k] = packh2(__expf(trans[(2 * k     ) * N_ + tid]),
                           __expf(trans[(2 * k +  1) * N_ + tid]));
            ub[k] = packh2(__expf(trans[(2 * k + 64) * N_ + tid]),
                           __expf(trans[(2 * k + 65) * N_ + tid]));
        }

        // init: ns_0, exact max, E_0 -> buffer 0
        float ns = st[tid] + em[base + tid];
        {
            float mxw = wave_max(ns);
            if (l == 0) pm2[0][w] = mxw;
        }
        __syncthreads();
        if (tid == 0) {
            int t0 = tg[bL];
            pathf[b] = pred[0] + pred[1] + st[t0] + em[base + t0];
        }
        float2 pmv0 = *(const float2*)pm2[0];
        float Mstar = fmaxf(pmv0.x, pmv0.y);
        ((_Float16*)Ehb[0])[tid] = (_Float16)__expf(ns - Mstar - C_BIAS);
        float Mcarry = Mstar;

        float pipe0 = em[base + (size_t)1 * N_ + tid];
        float pipe1 = em[base + (size_t)2 * N_ + tid];
        float pipe2 = em[base + (size_t)3 * N_ + tid];
        float pipe3 = em[base + (size_t)4 * N_ + tid];

#define FWD_STEP(T, SLOT, RD, WR)                                               \
        {                                                                       \
            lds_barrier();                                                      \
            float emv = SLOT;                                                   \
            int tpf = (T) + 4; if (tpf > TM - 1) tpf = TM - 1;                  \
            SLOT = em[base + (size_t)tpf * N_ + tid];                           \
            float2 pmv = *(const float2*)pm2[RD];                               \
            float Ms = fmaxf(pmv.x, pmv.y);                                     \
            float mk = Mlds[T];                                                 \
            float s = dot128(Ehb[RD], ua, ub);                                  \
            float nxt = __logf(s) + Mcarry + C_BIAS + emv;                      \
            ns = mk * nxt + (1.f - mk) * ns;                                    \
            float mxw = wave_max(ns);                                           \
            if (l == 0) pm2[WR][w] = mxw;                                       \
            ((_Float16*)Ehb[WR])[tid] = (_Float16)__expf(ns - Ms - C_BIAS);     \
            Mcarry = Ms;                                                        \
        }

        for (int tt = 1; tt + 3 < TM; tt += 4) {
            FWD_STEP(tt    , pipe0, 0, 1);
            FWD_STEP(tt + 1, pipe1, 1, 0);
            FWD_STEP(tt + 2, pipe2, 0, 1);
            FWD_STEP(tt + 3, pipe3, 1, 0);
        }
        FWD_STEP(TM - 3, pipe0, 0, 1);
        FWD_STEP(TM - 2, pipe1, 1, 0);
        FWD_STEP(TM - 1, pipe2, 0, 1);
#undef FWD_STEP

        alpha[b * N_ + tid] = ns;
    } else {
        // ================= BACKWARD =================
        float pacc = 0.f;
        for (int t = TM + tid; t < L_; t += 128) {
            int cur  = tg[bL + t];
            int prev = tg[bL + t - 1];
            pacc += mask[bL + t] * (trans[prev * N_ + cur] + em[base + (size_t)t * N_ + cur]);
        }
        pacc = wave_sum(pacc);
        if (l == 0) pred[w] = pacc;

        Mlds[tid]       = mask[bL + TM + tid];
        Mlds[tid + 128] = mask[bL + TM + tid + 128];

        // ET row fragment (states j paired): ua pair k = (j=2k, 2k+1), ub: j+64
        u32v ua, ub;
#pragma unroll
        for (int k = 0; k < 32; ++k) {
            float2 q0 = *(const float2*)(trans + tid * N_ + 2 * k);
            float2 q1 = *(const float2*)(trans + tid * N_ + 2 * k + 64);
            ua[k] = packh2(__expf(q0.x), __expf(q0.y));
            ub[k] = packh2(__expf(q1.x), __expf(q1.y));
        }

        // init at t=511: beta=0, v = em_511
        float bsc = 0.f;
        float v = em[base + (size_t)(L_ - 1) * N_ + tid];
        {
            float mxw = wave_max(v);
            if (l == 0) pm2[0][w] = mxw;
        }
        __syncthreads();
        if (tid == 0) pathb[b] = pred[0] + pred[1];
        float2 pmv0 = *(const float2*)pm2[0];
        float Mstar = fmaxf(pmv0.x, pmv0.y);
        ((_Float16*)Ehb[0])[tid] = (_Float16)__expf(v - Mstar - C_BIAS);
        float Mcarry = Mstar;

        float pipe0 = em[base + (size_t)510 * N_ + tid];
        float pipe1 = em[base + (size_t)509 * N_ + tid];
        float pipe2 = em[base + (size_t)508 * N_ + tid];
        float pipe3 = em[base + (size_t)507 * N_ + tid];

#define BWD_STEP(T, SLOT, RD, WR)                                               \
        {                                                                       \
            lds_barrier();                                                      \
            float emv = SLOT;                                                   \
            int tpf = (T) - 4; if (tpf < TM - 1) tpf = TM - 1;                  \
            SLOT = em[base + (size_t)tpf * N_ + tid];                           \
            float2 pmv = *(const float2*)pm2[RD];                               \
            float Ms = fmaxf(pmv.x, pmv.y);                                     \
            float mk = Mlds[(T) + 1 - TM];                                      \
            float s = dot128(Ehb[RD], ua, ub);                                  \
            float upd = __logf(s) + Mcarry + C_BIAS;                            \
            bsc = mk * upd + (1.f - mk) * bsc;                                  \
            v = bsc + emv;                                                      \
            float mxw = wave_max(v);                                            \
            if (l == 0) pm2[WR][w] = mxw;                                       \
            ((_Float16*)Ehb[WR])[tid] = (_Float16)__expf(v - Ms - C_BIAS);      \
            Mcarry = Ms;                                                        \
        }

        for (int tt = 510; tt >= 258; tt -= 4) {   // t = 510..255, 256 steps
            BWD_STEP(tt    , pipe0, 0, 1);
            BWD_STEP(tt - 1, pipe1, 1, 0);
            BWD_STEP(tt - 2, pipe2, 0, 1);
            BWD_STEP(tt - 3, pipe3, 1, 0);
        }
#undef BWD_STEP

        beta[b * N_ + tid] = bsc;
    }
}

// ---------------------------------------------------------------------------
__global__ __launch_bounds__(1024) void combine_kernel(
    const float* __restrict__ alpha, const float* __restrict__ beta,
    const float* __restrict__ pathf, const float* __restrict__ pathb,
    float* __restrict__ out)
{
    __shared__ float part[16];
    const int tid = threadIdx.x;
    const int w = tid >> 6;
    const int l = tid & 63;
    float acc = 0.f;
    for (int k = 0; k < 32; ++k) {
        int b = w * 32 + k;
        float2 av = *(const float2*)(alpha + b * N_ + 2 * l);
        float2 bv = *(const float2*)(beta  + b * N_ + 2 * l);
        float v0 = av.x + bv.x;
        float v1 = av.y + bv.y;
        float m = wave_max(fmaxf(v0, v1));
        float s = wave_sum(__expf(v0 - m) + __expf(v1 - m));
        if (l == 0) acc += m + __logf(s) - pathf[b] - pathb[b];
    }
    if (l == 0) part[w] = acc;
    __syncthreads();
    if (tid == 0) {
        float t = 0.f;
#pragma unroll
        for (int i = 0; i < 16; ++i) t += part[i];
        out[0] = t / (float)B_;
    }
}

// ---------------------------------------------------------------------------
extern "C" void kernel_launch(void* const* d_in, const int* in_sizes, int n_in,
                              void* d_out, int out_size, void* d_ws, size_t ws_size,
                              hipStream_t stream) {
    const float* emission    = (const float*)d_in[0];
    const int*   target      = (const int*)  d_in[1];
    const float* mask        = (const float*)d_in[2];
    const float* start_trans = (const float*)d_in[3];
    const float* trans       = (const float*)d_in[4];
    float* out = (float*)d_out;

    float* ws_f  = (float*)d_ws;
    float* alpha = ws_f;                    // 512*128
    float* beta  = ws_f + B_ * N_;          // 512*128
    float* pathf = ws_f + 2 * B_ * N_;      // 512
    float* pathb = ws_f + 2 * B_ * N_ + B_; // 512

    norm_kernel   <<<2 * B_, 128, 0, stream>>>(emission, target, mask, start_trans,
                                               trans, alpha, beta, pathf, pathb);
    combine_kernel<<<1, 1024, 0, stream>>>(alpha, beta, pathf, pathb, out);
}